// Round 6
// baseline (432.512 us; speedup 1.0000x reference)
//
#include <hip/hip_runtime.h>
#include <math.h>

#define B_BATCH 2048
#define N_PTS   2048

// ws layout: partials[2048][2][16] floats (256 KB), then counters[2048] int (8 KB)
#define CTR_OFF (B_BATCH * 32)

__global__ __launch_bounds__(256) void zero_counters(int* __restrict__ C) {
    const int i = blockIdx.x * blockDim.x + threadIdx.x;
    if (i < B_BATCH) C[i] = 0;
}

// ---------------- Fused: per-batch reduction + last-block 3x3 SVD ----------------
// acc layout: [0]=sum w, [1..3]=sum w*s, [4..6]=sum w*t, [7+3i+j]=sum w*t_i*s_j
// 2 blocks per batch (R4's best-measured structure), XCD-contiguous swizzle.
// Each block writes 16 partials; the second block to finish (device-scope
// atomicAdd on counter) runs the fp64 SVD inline on thread 0 — the 2048 SVD
// chains overlap with other batches' streaming instead of costing a dispatch.
__global__ __launch_bounds__(256, 2) void reduce_svd_kernel(
    const float* __restrict__ src, const float* __restrict__ tgt,
    const float* __restrict__ wts, float* __restrict__ ws,
    float* __restrict__ outR, float* __restrict__ outT)
{
    // XCD-contiguous swizzle: XCD k (blockIdx%8) works batches [k*256,(k+1)*256)
    const int phys = blockIdx.x;
    const int bid  = (phys & 7) * 512 + (phys >> 3);
    const int b    = bid >> 1;
    const int half = bid & 1;
    const int tid  = threadIdx.x;

    const float4* s4 = (const float4*)(src + (size_t)b * N_PTS * 3) + half * 768;
    const float4* t4 = (const float4*)(tgt + (size_t)b * N_PTS * 3) + half * 768;
    const float4* w4 = (const float4*)(wts + (size_t)b * N_PTS) + half * 256;

    // thread handles 4 points: 3 coord f4 per array + 1 weight f4 (7 loads, one round)
    float4 sv[3], tv[3], wq;
#pragma unroll
    for (int k = 0; k < 3; ++k) sv[k] = s4[3 * tid + k];
#pragma unroll
    for (int k = 0; k < 3; ++k) tv[k] = t4[3 * tid + k];
    wq = w4[tid];

    const float* sf = (const float*)sv;
    const float* tf = (const float*)tv;
    const float* wf = (const float*)&wq;

    float acc[16];
#pragma unroll
    for (int i = 0; i < 16; ++i) acc[i] = 0.f;

#pragma unroll
    for (int p = 0; p < 4; ++p) {
        const float w  = wf[p];
        const float sx = sf[3*p+0], sy = sf[3*p+1], sz = sf[3*p+2];
        const float tx = tf[3*p+0], ty = tf[3*p+1], tz = tf[3*p+2];
        const float wsx = w * sx, wsy = w * sy, wsz = w * sz;
        acc[0]  += w;
        acc[1]  += wsx;      acc[2]  += wsy;      acc[3]  += wsz;
        acc[4]  += w * tx;   acc[5]  += w * ty;   acc[6]  += w * tz;
        acc[7]  += tx * wsx; acc[8]  += tx * wsy; acc[9]  += tx * wsz;
        acc[10] += ty * wsx; acc[11] += ty * wsy; acc[12] += ty * wsz;
        acc[13] += tz * wsx; acc[14] += tz * wsy; acc[15] += tz * wsz;
    }

    // wave-level reduce (wave64)
#pragma unroll
    for (int i = 0; i < 16; ++i) {
#pragma unroll
        for (int off = 32; off > 0; off >>= 1)
            acc[i] += __shfl_down(acc[i], off, 64);
    }

    __shared__ float red[4][16];
    const int lane = tid & 63, wv_ = tid >> 6;
    if (lane == 0) {
#pragma unroll
        for (int i = 0; i < 16; ++i) red[wv_][i] = acc[i];
    }
    __syncthreads();
    if (tid < 16)
        ws[(size_t)b * 32 + half * 16 + tid] =
            red[0][tid] + red[1][tid] + red[2][tid] + red[3][tid];
    __syncthreads();

    if (tid != 0) return;

    // release our partial, arrive at the batch counter (device-scope)
    __threadfence();
    int* ctr = (int*)(ws + CTR_OFF);
    const int old = atomicAdd(&ctr[b], 1);
    if (old != 1) return;           // first arriver exits; second does the SVD
    __threadfence();                // acquire: other block's partial now visible

    const float* P = ws + (size_t)b * 32;
    float S[16];
#pragma unroll
    for (int i = 0; i < 16; ++i) S[i] = P[i] + P[16 + i];

    const double wtot = (double)S[0] + 1e-4;
    const double inv  = 1.0 / wtot;
    double sc[3] = { S[1]*inv, S[2]*inv, S[3]*inv };
    double tc[3] = { S[4]*inv, S[5]*inv, S[6]*inv };
    const double f = (wtot + 1e-4) * inv;   // exact centering correction

    double W[3][3];
#pragma unroll
    for (int i = 0; i < 3; ++i)
#pragma unroll
        for (int j = 0; j < 3; ++j)
            W[i][j] = (double)S[7 + 3*i + j] * inv - f * tc[i] * sc[j];

    // A = W^T W (symmetric)
    double A[3][3];
    for (int i = 0; i < 3; ++i)
        for (int j = 0; j < 3; ++j) {
            double s = 0.0;
            for (int k = 0; k < 3; ++k) s += W[k][i] * W[k][j];
            A[i][j] = s;
        }

    // cyclic Jacobi eigen-decomposition; quadratic convergence -> ~4 sweeps.
    double V[3][3] = {{1,0,0},{0,1,0},{0,0,1}};
    const double tr0 = fabs(A[0][0]) + fabs(A[1][1]) + fabs(A[2][2]) + 1e-300;
    for (int sweep = 0; sweep < 8; ++sweep) {
        double offd = fabs(A[0][1]) + fabs(A[0][2]) + fabs(A[1][2]);
        if (offd <= 1e-28 * tr0) break;
        for (int pq = 0; pq < 3; ++pq) {
            const int p = (pq == 2) ? 1 : 0;
            const int q = (pq == 0) ? 1 : 2;
            const double apq = A[p][q];
            if (fabs(apq) == 0.0) continue;
            const double tau = (A[q][q] - A[p][p]) / (2.0 * apq);
            const double tt  = (tau >= 0.0 ? 1.0 : -1.0) /
                               (fabs(tau) + sqrt(1.0 + tau * tau));
            const double c = 1.0 / sqrt(1.0 + tt * tt);
            const double s = tt * c;
            for (int k = 0; k < 3; ++k) {
                const double akp = A[k][p], akq = A[k][q];
                A[k][p] = c * akp - s * akq;
                A[k][q] = s * akp + c * akq;
            }
            for (int k = 0; k < 3; ++k) {
                const double apk = A[p][k], aqk = A[q][k];
                A[p][k] = c * apk - s * aqk;
                A[q][k] = s * apk + c * aqk;
            }
            for (int k = 0; k < 3; ++k) {
                const double vkp = V[k][p], vkq = V[k][q];
                V[k][p] = c * vkp - s * vkq;
                V[k][q] = s * vkp + c * vkq;
            }
        }
    }

    // sort eigenvalues descending (numpy returns descending singular values)
    double lam[3] = { A[0][0], A[1][1], A[2][2] };
    int idx[3] = {0, 1, 2};
    if (lam[idx[0]] < lam[idx[1]]) { int t_ = idx[0]; idx[0] = idx[1]; idx[1] = t_; }
    if (lam[idx[0]] < lam[idx[2]]) { int t_ = idx[0]; idx[0] = idx[2]; idx[2] = t_; }
    if (lam[idx[1]] < lam[idx[2]]) { int t_ = idx[1]; idx[1] = idx[2]; idx[2] = t_; }

    double v[3][3]; // sorted eigenvector columns: v[r][c]
#pragma unroll
    for (int c = 0; c < 3; ++c)
        for (int r = 0; r < 3; ++r) v[r][c] = V[r][idx[c]];

    // U columns via Gram-Schmidt of W*v_c, with fallbacks for tiny sigma
    double u[3][3];
    double col[3];
    for (int r = 0; r < 3; ++r)
        col[r] = W[r][0]*v[0][0] + W[r][1]*v[1][0] + W[r][2]*v[2][0];
    double s0 = sqrt(col[0]*col[0] + col[1]*col[1] + col[2]*col[2]);
    if (s0 > 1e-150) {
        for (int r = 0; r < 3; ++r) u[r][0] = col[r] / s0;
    } else {
        u[0][0] = 1.0; u[1][0] = 0.0; u[2][0] = 0.0;
    }
    for (int r = 0; r < 3; ++r)
        col[r] = W[r][0]*v[0][1] + W[r][1]*v[1][1] + W[r][2]*v[2][1];
    {
        double d01 = col[0]*u[0][0] + col[1]*u[1][0] + col[2]*u[2][0];
        for (int r = 0; r < 3; ++r) col[r] -= d01 * u[r][0];
        double s1 = sqrt(col[0]*col[0] + col[1]*col[1] + col[2]*col[2]);
        if (s1 > 1e-12 * (1.0 + s0)) {
            for (int r = 0; r < 3; ++r) u[r][1] = col[r] / s1;
        } else {
            double ax = fabs(u[0][0]), ay = fabs(u[1][0]), az = fabs(u[2][0]);
            double e[3] = {0, 0, 0};
            if (ax <= ay && ax <= az) e[0] = 1.0;
            else if (ay <= az)        e[1] = 1.0;
            else                      e[2] = 1.0;
            double p0 = u[1][0]*e[2] - u[2][0]*e[1];
            double p1 = u[2][0]*e[0] - u[0][0]*e[2];
            double p2 = u[0][0]*e[1] - u[1][0]*e[0];
            double pn = sqrt(p0*p0 + p1*p1 + p2*p2);
            u[0][1] = p0/pn; u[1][1] = p1/pn; u[2][1] = p2/pn;
        }
    }
    for (int r = 0; r < 3; ++r)
        col[r] = W[r][0]*v[0][2] + W[r][1]*v[1][2] + W[r][2]*v[2][2];
    {
        double d02 = col[0]*u[0][0] + col[1]*u[1][0] + col[2]*u[2][0];
        double d12 = col[0]*u[0][1] + col[1]*u[1][1] + col[2]*u[2][1];
        for (int r = 0; r < 3; ++r) col[r] -= d02 * u[r][0] + d12 * u[r][1];
        double s2 = sqrt(col[0]*col[0] + col[1]*col[1] + col[2]*col[2]);
        if (s2 > 1e-12 * (1.0 + s0)) {
            for (int r = 0; r < 3; ++r) u[r][2] = col[r] / s2;
        } else {
            // sigma3 ~ 0: u3 = u0 x u1 (R is gauge-invariant in this case)
            u[0][2] = u[1][0]*u[2][1] - u[2][0]*u[1][1];
            u[1][2] = u[2][0]*u[0][1] - u[0][0]*u[2][1];
            u[2][2] = u[0][0]*u[1][1] - u[1][0]*u[0][1];
        }
    }

    // d = sign(det(U) * det(V))
    double detU =
        u[0][0]*(u[1][1]*u[2][2] - u[2][1]*u[1][2]) -
        u[0][1]*(u[1][0]*u[2][2] - u[2][0]*u[1][2]) +
        u[0][2]*(u[1][0]*u[2][1] - u[2][0]*u[1][1]);
    double detV =
        v[0][0]*(v[1][1]*v[2][2] - v[2][1]*v[1][2]) -
        v[0][1]*(v[1][0]*v[2][2] - v[2][0]*v[1][2]) +
        v[0][2]*(v[1][0]*v[2][1] - v[2][0]*v[1][1]);
    const double d = (detU * detV >= 0.0) ? 1.0 : -1.0;

    // R = u0 v0^T + u1 v1^T + d * u2 v2^T ; t = tc - R*sc
    double R[3][3];
#pragma unroll
    for (int r = 0; r < 3; ++r)
#pragma unroll
        for (int c = 0; c < 3; ++c)
            R[r][c] = u[r][0]*v[c][0] + u[r][1]*v[c][1] + d * u[r][2]*v[c][2];

    float* Rb = outR + (size_t)b * 9;
#pragma unroll
    for (int r = 0; r < 3; ++r)
#pragma unroll
        for (int c = 0; c < 3; ++c)
            Rb[3*r + c] = (float)R[r][c];

    float* Tb = outT + (size_t)b * 3;
#pragma unroll
    for (int r = 0; r < 3; ++r)
        Tb[r] = (float)(tc[r] - (R[r][0]*sc[0] + R[r][1]*sc[1] + R[r][2]*sc[2]));
}

extern "C" void kernel_launch(void* const* d_in, const int* in_sizes, int n_in,
                              void* d_out, int out_size, void* d_ws, size_t ws_size,
                              hipStream_t stream) {
    const float* src = (const float*)d_in[0];   // (B,N,3)
    const float* tgt = (const float*)d_in[1];   // (B,N,3)
    const float* wts = (const float*)d_in[2];   // (B,1,N)
    float* outR = (float*)d_out;                // (B,3,3) flat
    float* outT = outR + (size_t)B_BATCH * 9;   // (B,3,1) flat
    float* ws   = (float*)d_ws;                 // partials + counters

    zero_counters<<<(B_BATCH + 255) / 256, 256, 0, stream>>>((int*)(ws + CTR_OFF));
    reduce_svd_kernel<<<B_BATCH * 2, 256, 0, stream>>>(src, tgt, wts, ws, outR, outT);
}

// Round 7
// 143.572 us; speedup vs baseline: 3.0125x; 3.0125x over previous
//
#include <hip/hip_runtime.h>
#include <math.h>

#define B_BATCH 2048
#define N_PTS   2048

// ---------------- Kernel 1: per-batch 16-way weighted reduction ----------------
// acc layout: [0]=sum w, [1..3]=sum w*s, [4..6]=sum w*t, [7+3i+j]=sum w*t_i*s_j
// 4 blocks/batch x 128 threads, 4 points/thread = 7 float4 loads issued in one
// round (R3 proved bigger per-thread load sets get serialized by the allocator;
// R6 proved device-scope fences nuke per-XCD L2 -> no fusion). All structures
// plateau at ~3.15 TB/s effective read (= m13 copy read half) -> ~37us floor.
__global__ __launch_bounds__(128) void reduce_kernel(
    const float* __restrict__ src, const float* __restrict__ tgt,
    const float* __restrict__ wts, float* __restrict__ sums)
{
    const int bid = blockIdx.x;
    const int b   = bid >> 2;
    const int qtr = bid & 3;
    const int tid = threadIdx.x;

    const float4* s4 = (const float4*)(src + (size_t)b * N_PTS * 3) + qtr * 384;
    const float4* t4 = (const float4*)(tgt + (size_t)b * N_PTS * 3) + qtr * 384;
    const float4* w4 = (const float4*)(wts + (size_t)b * N_PTS) + qtr * 128;

    // thread handles 4 points of this quarter: 3 coord f4 each + 1 weight f4
    float4 sv[3], tv[3], wq;
#pragma unroll
    for (int k = 0; k < 3; ++k) sv[k] = s4[3 * tid + k];
#pragma unroll
    for (int k = 0; k < 3; ++k) tv[k] = t4[3 * tid + k];
    wq = w4[tid];

    const float* sf = (const float*)sv;
    const float* tf = (const float*)tv;
    const float* wf = (const float*)&wq;

    float acc[16];
#pragma unroll
    for (int i = 0; i < 16; ++i) acc[i] = 0.f;

#pragma unroll
    for (int p = 0; p < 4; ++p) {
        const float w  = wf[p];
        const float sx = sf[3*p+0], sy = sf[3*p+1], sz = sf[3*p+2];
        const float tx = tf[3*p+0], ty = tf[3*p+1], tz = tf[3*p+2];
        const float wsx = w * sx, wsy = w * sy, wsz = w * sz;
        acc[0]  += w;
        acc[1]  += wsx;      acc[2]  += wsy;      acc[3]  += wsz;
        acc[4]  += w * tx;   acc[5]  += w * ty;   acc[6]  += w * tz;
        acc[7]  += tx * wsx; acc[8]  += tx * wsy; acc[9]  += tx * wsz;
        acc[10] += ty * wsx; acc[11] += ty * wsy; acc[12] += ty * wsz;
        acc[13] += tz * wsx; acc[14] += tz * wsy; acc[15] += tz * wsz;
    }

    // wave-level reduce (wave64)
#pragma unroll
    for (int i = 0; i < 16; ++i) {
#pragma unroll
        for (int off = 32; off > 0; off >>= 1)
            acc[i] += __shfl_down(acc[i], off, 64);
    }

    __shared__ float red[2][16];
    const int lane = tid & 63, wv_ = tid >> 6;
    if (lane == 0) {
#pragma unroll
        for (int i = 0; i < 16; ++i) red[wv_][i] = acc[i];
    }
    __syncthreads();
    if (tid < 16)
        sums[(size_t)bid * 16 + tid] = red[0][tid] + red[1][tid];
}

// ---------------- Kernel 2: per-batch 3x3 SVD + Kabsch assembly ----------------
__global__ __launch_bounds__(64) void svd_kernel(
    const float* __restrict__ sums,
    float* __restrict__ outR, float* __restrict__ outT)
{
    const int b = blockIdx.x * blockDim.x + threadIdx.x;
    if (b >= B_BATCH) return;
    const float* P = sums + (size_t)b * 64;
    float S[16];
#pragma unroll
    for (int i = 0; i < 16; ++i)
        S[i] = (P[i] + P[16 + i]) + (P[32 + i] + P[48 + i]);

    const double wtot = (double)S[0] + 1e-4;
    const double inv  = 1.0 / wtot;
    double sc[3] = { S[1]*inv, S[2]*inv, S[3]*inv };
    double tc[3] = { S[4]*inv, S[5]*inv, S[6]*inv };
    const double f = (wtot + 1e-4) * inv;   // exact centering correction

    double W[3][3];
#pragma unroll
    for (int i = 0; i < 3; ++i)
#pragma unroll
        for (int j = 0; j < 3; ++j)
            W[i][j] = (double)S[7 + 3*i + j] * inv - f * tc[i] * sc[j];

    // A = W^T W (symmetric)
    double A[3][3];
    for (int i = 0; i < 3; ++i)
        for (int j = 0; j < 3; ++j) {
            double s = 0.0;
            for (int k = 0; k < 3; ++k) s += W[k][i] * W[k][j];
            A[i][j] = s;
        }

    // cyclic Jacobi eigen-decomposition; quadratic convergence -> <=5 sweeps.
    double V[3][3] = {{1,0,0},{0,1,0},{0,0,1}};
    const double tr0 = fabs(A[0][0]) + fabs(A[1][1]) + fabs(A[2][2]) + 1e-300;
    for (int sweep = 0; sweep < 5; ++sweep) {
        double offd = fabs(A[0][1]) + fabs(A[0][2]) + fabs(A[1][2]);
        if (offd <= 1e-24 * tr0) break;
        for (int pq = 0; pq < 3; ++pq) {
            const int p = (pq == 2) ? 1 : 0;
            const int q = (pq == 0) ? 1 : 2;
            const double apq = A[p][q];
            if (fabs(apq) == 0.0) continue;
            const double tau = (A[q][q] - A[p][p]) / (2.0 * apq);
            const double tt  = (tau >= 0.0 ? 1.0 : -1.0) /
                               (fabs(tau) + sqrt(1.0 + tau * tau));
            const double c = 1.0 / sqrt(1.0 + tt * tt);
            const double s = tt * c;
            for (int k = 0; k < 3; ++k) {
                const double akp = A[k][p], akq = A[k][q];
                A[k][p] = c * akp - s * akq;
                A[k][q] = s * akp + c * akq;
            }
            for (int k = 0; k < 3; ++k) {
                const double apk = A[p][k], aqk = A[q][k];
                A[p][k] = c * apk - s * aqk;
                A[q][k] = s * apk + c * aqk;
            }
            for (int k = 0; k < 3; ++k) {
                const double vkp = V[k][p], vkq = V[k][q];
                V[k][p] = c * vkp - s * vkq;
                V[k][q] = s * vkp + c * vkq;
            }
        }
    }

    // sort eigenvalues descending (numpy returns descending singular values)
    double lam[3] = { A[0][0], A[1][1], A[2][2] };
    int idx[3] = {0, 1, 2};
    if (lam[idx[0]] < lam[idx[1]]) { int t_ = idx[0]; idx[0] = idx[1]; idx[1] = t_; }
    if (lam[idx[0]] < lam[idx[2]]) { int t_ = idx[0]; idx[0] = idx[2]; idx[2] = t_; }
    if (lam[idx[1]] < lam[idx[2]]) { int t_ = idx[1]; idx[1] = idx[2]; idx[2] = t_; }

    double v[3][3]; // sorted eigenvector columns: v[r][c]
#pragma unroll
    for (int c = 0; c < 3; ++c)
        for (int r = 0; r < 3; ++r) v[r][c] = V[r][idx[c]];

    // U columns via Gram-Schmidt of W*v_c, with fallbacks for tiny sigma
    double u[3][3];
    double col[3];
    for (int r = 0; r < 3; ++r)
        col[r] = W[r][0]*v[0][0] + W[r][1]*v[1][0] + W[r][2]*v[2][0];
    double s0 = sqrt(col[0]*col[0] + col[1]*col[1] + col[2]*col[2]);
    if (s0 > 1e-150) {
        for (int r = 0; r < 3; ++r) u[r][0] = col[r] / s0;
    } else {
        u[0][0] = 1.0; u[1][0] = 0.0; u[2][0] = 0.0;
    }
    for (int r = 0; r < 3; ++r)
        col[r] = W[r][0]*v[0][1] + W[r][1]*v[1][1] + W[r][2]*v[2][1];
    {
        double d01 = col[0]*u[0][0] + col[1]*u[1][0] + col[2]*u[2][0];
        for (int r = 0; r < 3; ++r) col[r] -= d01 * u[r][0];
        double s1 = sqrt(col[0]*col[0] + col[1]*col[1] + col[2]*col[2]);
        if (s1 > 1e-12 * (1.0 + s0)) {
            for (int r = 0; r < 3; ++r) u[r][1] = col[r] / s1;
        } else {
            double ax = fabs(u[0][0]), ay = fabs(u[1][0]), az = fabs(u[2][0]);
            double e[3] = {0, 0, 0};
            if (ax <= ay && ax <= az) e[0] = 1.0;
            else if (ay <= az)        e[1] = 1.0;
            else                      e[2] = 1.0;
            double p0 = u[1][0]*e[2] - u[2][0]*e[1];
            double p1 = u[2][0]*e[0] - u[0][0]*e[2];
            double p2 = u[0][0]*e[1] - u[1][0]*e[0];
            double pn = sqrt(p0*p0 + p1*p1 + p2*p2);
            u[0][1] = p0/pn; u[1][1] = p1/pn; u[2][1] = p2/pn;
        }
    }
    for (int r = 0; r < 3; ++r)
        col[r] = W[r][0]*v[0][2] + W[r][1]*v[1][2] + W[r][2]*v[2][2];
    {
        double d02 = col[0]*u[0][0] + col[1]*u[1][0] + col[2]*u[2][0];
        double d12 = col[0]*u[0][1] + col[1]*u[1][1] + col[2]*u[2][1];
        for (int r = 0; r < 3; ++r) col[r] -= d02 * u[r][0] + d12 * u[r][1];
        double s2 = sqrt(col[0]*col[0] + col[1]*col[1] + col[2]*col[2]);
        if (s2 > 1e-12 * (1.0 + s0)) {
            for (int r = 0; r < 3; ++r) u[r][2] = col[r] / s2;
        } else {
            // sigma3 ~ 0: u3 = u0 x u1 (R is gauge-invariant in this case)
            u[0][2] = u[1][0]*u[2][1] - u[2][0]*u[1][1];
            u[1][2] = u[2][0]*u[0][1] - u[0][0]*u[2][1];
            u[2][2] = u[0][0]*u[1][1] - u[1][0]*u[0][1];
        }
    }

    // d = sign(det(U) * det(V))
    double detU =
        u[0][0]*(u[1][1]*u[2][2] - u[2][1]*u[1][2]) -
        u[0][1]*(u[1][0]*u[2][2] - u[2][0]*u[1][2]) +
        u[0][2]*(u[1][0]*u[2][1] - u[2][0]*u[1][1]);
    double detV =
        v[0][0]*(v[1][1]*v[2][2] - v[2][1]*v[1][2]) -
        v[0][1]*(v[1][0]*v[2][2] - v[2][0]*v[1][2]) +
        v[0][2]*(v[1][0]*v[2][1] - v[2][0]*v[1][1]);
    const double d = (detU * detV >= 0.0) ? 1.0 : -1.0;

    // R = u0 v0^T + u1 v1^T + d * u2 v2^T ; t = tc - R*sc
    double R[3][3];
#pragma unroll
    for (int r = 0; r < 3; ++r)
#pragma unroll
        for (int c = 0; c < 3; ++c)
            R[r][c] = u[r][0]*v[c][0] + u[r][1]*v[c][1] + d * u[r][2]*v[c][2];

    float* Rb = outR + (size_t)b * 9;
#pragma unroll
    for (int r = 0; r < 3; ++r)
#pragma unroll
        for (int c = 0; c < 3; ++c)
            Rb[3*r + c] = (float)R[r][c];

    float* Tb = outT + (size_t)b * 3;
#pragma unroll
    for (int r = 0; r < 3; ++r)
        Tb[r] = (float)(tc[r] - (R[r][0]*sc[0] + R[r][1]*sc[1] + R[r][2]*sc[2]));
}

extern "C" void kernel_launch(void* const* d_in, const int* in_sizes, int n_in,
                              void* d_out, int out_size, void* d_ws, size_t ws_size,
                              hipStream_t stream) {
    const float* src = (const float*)d_in[0];   // (B,N,3)
    const float* tgt = (const float*)d_in[1];   // (B,N,3)
    const float* wts = (const float*)d_in[2];   // (B,1,N)
    float* outR = (float*)d_out;                // (B,3,3) flat
    float* outT = outR + (size_t)B_BATCH * 9;   // (B,3,1) flat
    float* sums = (float*)d_ws;                 // (B,4,16) partial sums

    reduce_kernel<<<B_BATCH * 4, 128, 0, stream>>>(src, tgt, wts, sums);
    svd_kernel<<<B_BATCH / 64, 64, 0, stream>>>(sums, outR, outT);
}